// Round 1
// baseline (429.966 us; speedup 1.0000x reference)
//
#include <hip/hip_runtime.h>

constexpr int Bsz  = 8;
constexpr int Vsz  = 8192;
constexpr int OUTC = 1280;

// ---------------- transpose [B, C, HW] -> [B, HW, C] ----------------
// block (32,8); each block moves a 32x32 tile through padded LDS.
template <int C, int HW>
__global__ __launch_bounds__(256) void transpose_kernel(const float* __restrict__ in,
                                                        float* __restrict__ out) {
    __shared__ float tile[32][33];  // +1 pad: stride-33 reads are bank-conflict-free
    const int b   = blockIdx.z;
    const int hw0 = blockIdx.x * 32;
    const int c0  = blockIdx.y * 32;   // C is a multiple of 32, always in-bounds
    const float* inb  = in  + (size_t)b * C * HW;
    float*       outb = out + (size_t)b * C * HW;
    const int tx = threadIdx.x;  // 0..31
    const int ty = threadIdx.y;  // 0..7
#pragma unroll
    for (int k = 0; k < 4; ++k) {
        const int c  = c0 + ty + 8 * k;
        const int hw = hw0 + tx;                       // coalesced read along HW
        tile[ty + 8 * k][tx] = (hw < HW) ? inb[(size_t)c * HW + hw] : 0.0f;
    }
    __syncthreads();
#pragma unroll
    for (int k = 0; k < 4; ++k) {
        const int hw = hw0 + ty + 8 * k;
        const int c  = c0 + tx;                        // coalesced write along C
        if (hw < HW) outb[(size_t)hw * C + c] = tile[tx][ty + 8 * k];
    }
}

// ---------------- main sampler, channel-last inputs ----------------
// One block per (b, v). 320 threads; thread t produces float4 of channels 4t..4t+3.
// Wave 0 -> fm3 (256 ch), waves 1-2 -> fm4 (512 ch), waves 3-4 -> fm5 (512 ch):
// level branch is wave-uniform.
__global__ __launch_bounds__(320) void sample_t(const float* __restrict__ coords,
                                                const float* __restrict__ t3,
                                                const float* __restrict__ t4,
                                                const float* __restrict__ t5,
                                                float* __restrict__ out) {
    const int blk = blockIdx.x;
    const int b = blk & 7;    // batch == XCD round-robin slot -> per-XCD L2 locality
    const int v = blk >> 3;
    const float x = coords[(size_t)(b * Vsz + v) * 2 + 0];
    const float y = coords[(size_t)(b * Vsz + v) * 2 + 1];

    const int t = threadIdx.x;  // 0..319
    const float* src; int C, W, HW, lc; float sx, sy;
    if (t < 64) {
        src = t3; C = 256; W = 56; HW = 3136; lc = 4 * t;       sx = x * 0.125f;   sy = y * 0.125f;
    } else if (t < 192) {
        src = t4; C = 512; W = 28; HW = 784;  lc = 4 * t - 256; sx = x * 0.0625f;  sy = y * 0.0625f;
    } else {
        src = t5; C = 512; W = 14; HW = 196;  lc = 4 * t - 768; sx = x * 0.03125f; sy = y * 0.03125f;
    }
    // exact torch-style corner weights (vanish at integer coords)
    const float fx1 = floorf(sx), fx2 = ceilf(sx);
    const float fy1 = floorf(sy), fy2 = ceilf(sy);
    const int xi1 = (int)fx1, xi2 = (int)fx2, yi1 = (int)fy1, yi2 = (int)fy2;
    const float wx1 = fx2 - sx, wx2 = sx - fx1;
    const float wy1 = fy2 - sy, wy2 = sy - fy1;
    const float w11 = wx1 * wy1, w12 = wx1 * wy2, w21 = wx2 * wy1, w22 = wx2 * wy2;

    const float* basep = src + (size_t)b * C * HW + lc;
    const float4 a11 = *(const float4*)(basep + (size_t)(yi1 * W + xi1) * C);
    const float4 a12 = *(const float4*)(basep + (size_t)(yi2 * W + xi1) * C);
    const float4 a21 = *(const float4*)(basep + (size_t)(yi1 * W + xi2) * C);
    const float4 a22 = *(const float4*)(basep + (size_t)(yi2 * W + xi2) * C);

    float4 r;
    r.x = a11.x * w11 + a12.x * w12 + a21.x * w21 + a22.x * w22;
    r.y = a11.y * w11 + a12.y * w12 + a21.y * w21 + a22.y * w22;
    r.z = a11.z * w11 + a12.z * w12 + a21.z * w21 + a22.z * w22;
    r.w = a11.w * w11 + a12.w * w12 + a21.w * w21 + a22.w * w22;
    *(float4*)(out + (size_t)(b * Vsz + v) * OUTC + 4 * t) = r;
}

// ---------------- fallback: sample straight from [B, C, H, W] ----------------
// Used only if ws_size can't hold the transposed maps. Strided gathers, slower.
__global__ __launch_bounds__(320) void sample_direct(const float* __restrict__ coords,
                                                     const float* __restrict__ fm3,
                                                     const float* __restrict__ fm4,
                                                     const float* __restrict__ fm5,
                                                     float* __restrict__ out) {
    const int blk = blockIdx.x;
    const int b = blk & 7;
    const int v = blk >> 3;
    const float x = coords[(size_t)(b * Vsz + v) * 2 + 0];
    const float y = coords[(size_t)(b * Vsz + v) * 2 + 1];

    const int t = threadIdx.x;
    const float* src; int C, W, HW, lc; float sx, sy;
    if (t < 64) {
        src = fm3; C = 256; W = 56; HW = 3136; lc = 4 * t;       sx = x * 0.125f;   sy = y * 0.125f;
    } else if (t < 192) {
        src = fm4; C = 512; W = 28; HW = 784;  lc = 4 * t - 256; sx = x * 0.0625f;  sy = y * 0.0625f;
    } else {
        src = fm5; C = 512; W = 14; HW = 196;  lc = 4 * t - 768; sx = x * 0.03125f; sy = y * 0.03125f;
    }
    const float fx1 = floorf(sx), fx2 = ceilf(sx);
    const float fy1 = floorf(sy), fy2 = ceilf(sy);
    const int xi1 = (int)fx1, xi2 = (int)fx2, yi1 = (int)fy1, yi2 = (int)fy2;
    const float wx1 = fx2 - sx, wx2 = sx - fx1;
    const float wy1 = fy2 - sy, wy2 = sy - fy1;
    const float w11 = wx1 * wy1, w12 = wx1 * wy2, w21 = wx2 * wy1, w22 = wx2 * wy2;

    const float* baseb = src + (size_t)b * C * HW;
    const int o11 = yi1 * W + xi1, o12 = yi2 * W + xi1, o21 = yi1 * W + xi2, o22 = yi2 * W + xi2;
    float4 r;
    float* rp = (float*)&r;
#pragma unroll
    for (int j = 0; j < 4; ++j) {
        const float* pc = baseb + (size_t)(lc + j) * HW;
        rp[j] = pc[o11] * w11 + pc[o12] * w12 + pc[o21] * w21 + pc[o22] * w22;
    }
    *(float4*)(out + (size_t)(b * Vsz + v) * OUTC + 4 * t) = r;
}

extern "C" void kernel_launch(void* const* d_in, const int* in_sizes, int n_in,
                              void* d_out, int out_size, void* d_ws, size_t ws_size,
                              hipStream_t stream) {
    const float* c   = (const float*)d_in[0];
    const float* fm3 = (const float*)d_in[1];
    const float* fm4 = (const float*)d_in[2];
    const float* fm5 = (const float*)d_in[3];
    float* out = (float*)d_out;

    const size_t n3 = (size_t)Bsz * 256 * 3136;
    const size_t n4 = (size_t)Bsz * 512 * 784;
    const size_t n5 = (size_t)Bsz * 512 * 196;
    const size_t need = (n3 + n4 + n5) * sizeof(float);  // ~41.7 MB

    if (ws_size >= need) {
        float* t3 = (float*)d_ws;
        float* t4 = t3 + n3;
        float* t5 = t4 + n4;
        transpose_kernel<256, 3136><<<dim3(98, 8,  Bsz), dim3(32, 8), 0, stream>>>(fm3, t3);
        transpose_kernel<512, 784 ><<<dim3(25, 16, Bsz), dim3(32, 8), 0, stream>>>(fm4, t4);
        transpose_kernel<512, 196 ><<<dim3(7,  16, Bsz), dim3(32, 8), 0, stream>>>(fm5, t5);
        sample_t<<<Bsz * Vsz, 320, 0, stream>>>(c, t3, t4, t5, out);
    } else {
        sample_direct<<<Bsz * Vsz, 320, 0, stream>>>(c, fm3, fm4, fm5, out);
    }
}

// Round 2
// 397.244 us; speedup vs baseline: 1.0824x; 1.0824x over previous
//
#include <hip/hip_runtime.h>

typedef float floatx4 __attribute__((ext_vector_type(4)));

constexpr int Bsz  = 8;
constexpr int Vsz  = 8192;
constexpr int OUTC = 1280;

// ---------------- transpose [B, C, HW] -> [B, HW, C] ----------------
// Flat 1D grid with batch in the low 3 bits: XCD round-robin dispatch puts
// batch b's tiles (and thus its L2-resident transposed map) on XCD b, matching
// the samplers' b = blockIdx&7 mapping. Input reads are single-use -> NT loads.
template <int C, int HW, int NTILE_HW>
__global__ __launch_bounds__(256) void transpose_kernel(const float* __restrict__ in,
                                                        float* __restrict__ out) {
    __shared__ float tile[32][33];  // +1 pad: conflict-free transpose
    const int id   = blockIdx.x;
    const int b    = id & 7;
    const int rest = id >> 3;
    const int hw0  = (rest % NTILE_HW) * 32;
    const int c0   = (rest / NTILE_HW) * 32;   // C multiple of 32
    const float* inb  = in  + (size_t)b * C * HW;
    float*       outb = out + (size_t)b * C * HW;
    const int tx = threadIdx.x & 31;
    const int ty = threadIdx.x >> 5;   // 0..7
#pragma unroll
    for (int k = 0; k < 4; ++k) {
        const int c  = c0 + ty + 8 * k;
        const int hw = hw0 + tx;                       // coalesced read along HW
        tile[ty + 8 * k][tx] =
            (hw < HW) ? __builtin_nontemporal_load(inb + (size_t)c * HW + hw) : 0.0f;
    }
    __syncthreads();
#pragma unroll
    for (int k = 0; k < 4; ++k) {
        const int hw = hw0 + ty + 8 * k;
        const int c  = c0 + tx;                        // coalesced write along C (cached: re-read soon)
        if (hw < HW) outb[(size_t)hw * C + c] = tile[tx][ty + 8 * k];
    }
}

// ---------------- level-3 sampler (C=256, 56x56 map) ----------------
// 256 threads = 4 waves; wave w samples point v = 4*vg + w; lane l covers
// channels 4l..4l+3. Working set/XCD: 3.21 MB < 4 MB L2. NT output stores.
__global__ __launch_bounds__(256) void sample3(const float* __restrict__ coords,
                                               const float* __restrict__ t3,
                                               float* __restrict__ out) {
    const int blk  = blockIdx.x;
    const int b    = blk & 7;          // batch == XCD slot
    const int vg   = blk >> 3;         // 0..2047
    const int wave = threadIdx.x >> 6;
    const int lane = threadIdx.x & 63;
    const int v    = vg * 4 + wave;
    const size_t pidx = (size_t)b * Vsz + v;

    const float sx = coords[pidx * 2 + 0] * 0.125f;
    const float sy = coords[pidx * 2 + 1] * 0.125f;
    const float fx1 = floorf(sx), fx2 = ceilf(sx);
    const float fy1 = floorf(sy), fy2 = ceilf(sy);
    const int xi1 = (int)fx1, xi2 = (int)fx2, yi1 = (int)fy1, yi2 = (int)fy2;
    const float wx1 = fx2 - sx, wx2 = sx - fx1;
    const float wy1 = fy2 - sy, wy2 = sy - fy1;
    const float w11 = wx1 * wy1, w12 = wx1 * wy2, w21 = wx2 * wy1, w22 = wx2 * wy2;

    const float* basep = t3 + (size_t)b * 256 * 3136 + 4 * lane;
    const floatx4 a11 = *(const floatx4*)(basep + (size_t)(yi1 * 56 + xi1) * 256);
    const floatx4 a12 = *(const floatx4*)(basep + (size_t)(yi2 * 56 + xi1) * 256);
    const floatx4 a21 = *(const floatx4*)(basep + (size_t)(yi1 * 56 + xi2) * 256);
    const floatx4 a22 = *(const floatx4*)(basep + (size_t)(yi2 * 56 + xi2) * 256);

    const floatx4 r = a11 * w11 + a12 * w12 + a21 * w21 + a22 * w22;
    __builtin_nontemporal_store(r, (floatx4*)(out + pidx * OUTC + 4 * lane));
}

// ---------------- level-4+5 sampler (C=512 each, 28x28 + 14x14) ----------------
// 256 threads, one point per block. Waves 0-1 -> fm4 channels, waves 2-3 -> fm5
// (wave-uniform branch). Working set/XCD: 1.6 + 0.4 = 2.0 MB < 4 MB L2.
__global__ __launch_bounds__(256) void sample45(const float* __restrict__ coords,
                                                const float* __restrict__ t4,
                                                const float* __restrict__ t5,
                                                float* __restrict__ out) {
    const int blk = blockIdx.x;
    const int b   = blk & 7;
    const int v   = blk >> 3;
    const size_t pidx = (size_t)b * Vsz + v;
    const float x = coords[pidx * 2 + 0];
    const float y = coords[pidx * 2 + 1];

    const int t = threadIdx.x;
    const float* src; int W, HW, lc; float s;
    if (t < 128) { src = t4; W = 28; HW = 784; lc = 4 * t;       s = 0.0625f;  }
    else         { src = t5; W = 14; HW = 196; lc = 4 * t - 512; s = 0.03125f; }
    const int oc = 256 + 4 * t;  // holds for both halves: t=128 -> 768

    const float sx = x * s, sy = y * s;
    const float fx1 = floorf(sx), fx2 = ceilf(sx);
    const float fy1 = floorf(sy), fy2 = ceilf(sy);
    const int xi1 = (int)fx1, xi2 = (int)fx2, yi1 = (int)fy1, yi2 = (int)fy2;
    const float wx1 = fx2 - sx, wx2 = sx - fx1;
    const float wy1 = fy2 - sy, wy2 = sy - fy1;
    const float w11 = wx1 * wy1, w12 = wx1 * wy2, w21 = wx2 * wy1, w22 = wx2 * wy2;

    const float* basep = src + (size_t)b * 512 * HW + lc;
    const floatx4 a11 = *(const floatx4*)(basep + (size_t)(yi1 * W + xi1) * 512);
    const floatx4 a12 = *(const floatx4*)(basep + (size_t)(yi2 * W + xi1) * 512);
    const floatx4 a21 = *(const floatx4*)(basep + (size_t)(yi1 * W + xi2) * 512);
    const floatx4 a22 = *(const floatx4*)(basep + (size_t)(yi2 * W + xi2) * 512);

    const floatx4 r = a11 * w11 + a12 * w12 + a21 * w21 + a22 * w22;
    __builtin_nontemporal_store(r, (floatx4*)(out + pidx * OUTC + oc));
}

// ---------------- fallback: sample straight from [B, C, H, W] ----------------
__global__ __launch_bounds__(320) void sample_direct(const float* __restrict__ coords,
                                                     const float* __restrict__ fm3,
                                                     const float* __restrict__ fm4,
                                                     const float* __restrict__ fm5,
                                                     float* __restrict__ out) {
    const int blk = blockIdx.x;
    const int b = blk & 7;
    const int v = blk >> 3;
    const float x = coords[(size_t)(b * Vsz + v) * 2 + 0];
    const float y = coords[(size_t)(b * Vsz + v) * 2 + 1];

    const int t = threadIdx.x;
    const float* src; int C, W, HW, lc; float sx, sy;
    if (t < 64) {
        src = fm3; C = 256; W = 56; HW = 3136; lc = 4 * t;       sx = x * 0.125f;   sy = y * 0.125f;
    } else if (t < 192) {
        src = fm4; C = 512; W = 28; HW = 784;  lc = 4 * t - 256; sx = x * 0.0625f;  sy = y * 0.0625f;
    } else {
        src = fm5; C = 512; W = 14; HW = 196;  lc = 4 * t - 768; sx = x * 0.03125f; sy = y * 0.03125f;
    }
    const float fx1 = floorf(sx), fx2 = ceilf(sx);
    const float fy1 = floorf(sy), fy2 = ceilf(sy);
    const int xi1 = (int)fx1, xi2 = (int)fx2, yi1 = (int)fy1, yi2 = (int)fy2;
    const float wx1 = fx2 - sx, wx2 = sx - fx1;
    const float wy1 = fy2 - sy, wy2 = sy - fy1;
    const float w11 = wx1 * wy1, w12 = wx1 * wy2, w21 = wx2 * wy1, w22 = wx2 * wy2;

    const float* baseb = src + (size_t)b * C * HW;
    const int o11 = yi1 * W + xi1, o12 = yi2 * W + xi1, o21 = yi1 * W + xi2, o22 = yi2 * W + xi2;
    float4 r;
    float* rp = (float*)&r;
#pragma unroll
    for (int j = 0; j < 4; ++j) {
        const float* pc = baseb + (size_t)(lc + j) * HW;
        rp[j] = pc[o11] * w11 + pc[o12] * w12 + pc[o21] * w21 + pc[o22] * w22;
    }
    *(float4*)(out + (size_t)(b * Vsz + v) * OUTC + 4 * t) = r;
}

extern "C" void kernel_launch(void* const* d_in, const int* in_sizes, int n_in,
                              void* d_out, int out_size, void* d_ws, size_t ws_size,
                              hipStream_t stream) {
    const float* c   = (const float*)d_in[0];
    const float* fm3 = (const float*)d_in[1];
    const float* fm4 = (const float*)d_in[2];
    const float* fm5 = (const float*)d_in[3];
    float* out = (float*)d_out;

    const size_t n3 = (size_t)Bsz * 256 * 3136;
    const size_t n4 = (size_t)Bsz * 512 * 784;
    const size_t n5 = (size_t)Bsz * 512 * 196;
    const size_t need = (n3 + n4 + n5) * sizeof(float);  // ~41.7 MB

    if (ws_size >= need) {
        float* t3 = (float*)d_ws;
        float* t4 = t3 + n3;
        float* t5 = t4 + n4;
        // NTILE_HW: 3136/32=98 exact; 784 -> 25; 196 -> 7
        transpose_kernel<256, 3136, 98><<<98 * 8 * 8,  256, 0, stream>>>(fm3, t3);
        transpose_kernel<512, 784,  25><<<25 * 16 * 8, 256, 0, stream>>>(fm4, t4);
        transpose_kernel<512, 196,  7 ><<<7 * 16 * 8,  256, 0, stream>>>(fm5, t5);
        sample45<<<Bsz * Vsz, 256, 0, stream>>>(c, t4, t5, out);
        sample3 <<<Bsz * (Vsz / 4), 256, 0, stream>>>(c, t3, out);
    } else {
        sample_direct<<<Bsz * Vsz, 320, 0, stream>>>(c, fm3, fm4, fm5, out);
    }
}